// Round 1
// baseline (779.882 us; speedup 1.0000x reference)
//
#include <hip/hip_runtime.h>
#include <hip/hip_bf16.h>
#include <stdint.h>

#define SEQ 2048
#define DDIM 768
#define KF 24
#define NKV 48

typedef __attribute__((ext_vector_type(8))) short short8;
typedef __attribute__((ext_vector_type(4))) float f32x4;

__device__ __forceinline__ unsigned short f2bf(float f) {
    union { float f; uint32_t u; } v; v.f = f;
    uint32_t u = v.u;
    uint32_t r = (u + 0x7fff + ((u >> 16) & 1)) >> 16;
    return (unsigned short)r;
}

// ---------------- prep kernels ----------------

__global__ void k_cast_x(const float* __restrict__ x, unsigned short* __restrict__ xb, int n) {
    int i = blockIdx.x * blockDim.x + threadIdx.x;
    if (i < n) xb[i] = f2bf(x[i]);
}

// MbT[kv][e][d] = bf16(M_kv[d][e]);  kv<24 -> M_plus[kv], else M_minus[kv-24]
__global__ void k_transpose_M(const float* __restrict__ Mp, const float* __restrict__ Mm,
                              unsigned short* __restrict__ MbT) {
    __shared__ unsigned short lt[64][65];
    int b = blockIdx.x;
    int kv = b / 144; int rem = b % 144;
    int dt = rem / 12;   // d tile
    int et = rem % 12;   // e tile
    const float* src = (kv < KF) ? (Mp + (size_t)kv * DDIM * DDIM)
                                 : (Mm + (size_t)(kv - KF) * DDIM * DDIM);
    int t = threadIdx.x;
    int c  = t & 63;     // e-local on read, d-local on write
    int r4 = t >> 6;     // 0..3
    int d0 = dt * 64, e0 = et * 64;
#pragma unroll
    for (int p = 0; p < 16; ++p) {
        int row = p * 4 + r4;   // d-local
        float v = src[(size_t)(d0 + row) * DDIM + e0 + c];
        lt[c][row] = f2bf(v);   // store transposed: lt[e-local][d-local]
    }
    __syncthreads();
    unsigned short* dst = MbT + (size_t)kv * DDIM * DDIM;
#pragma unroll
    for (int p = 0; p < 16; ++p) {
        int erow = p * 4 + r4;
        dst[(size_t)(e0 + erow) * DDIM + d0 + c] = lt[erow][c];
    }
}

// Tmat[kv][m][a][b] = f_kv(128*m + a - b), zero for negative lag.
// f_kv(tau) = phi[tau][k] * ((kv>=24 && tau odd) ? -1 : 1)
__global__ void k_build_T(const float* __restrict__ phi, unsigned short* __restrict__ Tmat) {
    __shared__ float phiL[256];
    int b = blockIdx.x;          // kv*16 + m
    int kv = b >> 4; int m = b & 15;
    int k = kv % KF;
    bool neg = (kv >= KF);
    int t = threadIdx.x;
    int tau = 128 * m - 127 + t; // t in [0,255]
    float v = 0.f;
    if (t < 255 && tau >= 0 && tau < SEQ) {
        v = phi[(size_t)tau * KF + k];
        if (neg && (tau & 1)) v = -v;
    }
    phiL[t] = v;
    __syncthreads();
    unsigned short* dst = Tmat + (size_t)b * (128 * 128);
#pragma unroll
    for (int q = 0; q < 64; ++q) {
        int lin = q * 256 + t;
        int a = lin >> 7, bb = lin & 127;
        dst[lin] = f2bf(phiL[a - bb + 127]);
    }
}

// ---------------- GEMM core helpers ----------------
// LDS tiles are [128 rows][8 slots of 8 bf16], slot XOR-swizzled by (row&7).

__device__ __forceinline__ void stage_tile(const unsigned short* __restrict__ src, int ld,
                                           unsigned short* dst, int tid) {
#pragma unroll
    for (int p = 0; p < 4; ++p) {
        int s = p * 256 + tid;
        int row = s >> 3, sl = s & 7;
        uint4 v = *(const uint4*)(src + (size_t)row * ld + sl * 8);
        *(uint4*)(dst + row * 64 + ((sl ^ (row & 7)) << 3)) = v;
    }
}

__device__ __forceinline__ void mfma_tile(const unsigned short* As, const unsigned short* Bs,
                                          int lane, int wm, int wn, f32x4 acc[4][4]) {
#pragma unroll
    for (int kk = 0; kk < 2; ++kk) {
        int slot = kk * 4 + (lane >> 4);
        short8 av[4], bv[4];
#pragma unroll
        for (int m = 0; m < 4; ++m) {
            int row = wm * 64 + m * 16 + (lane & 15);
            av[m] = *(const short8*)(As + row * 64 + ((slot ^ (row & 7)) << 3));
        }
#pragma unroll
        for (int n = 0; n < 4; ++n) {
            int row = wn * 64 + n * 16 + (lane & 15);
            bv[n] = *(const short8*)(Bs + row * 64 + ((slot ^ (row & 7)) << 3));
        }
#pragma unroll
        for (int m = 0; m < 4; ++m)
#pragma unroll
            for (int n = 0; n < 4; ++n)
                acc[m][n] = __builtin_amdgcn_mfma_f32_16x16x32_bf16(av[m], bv[n], acc[m][n], 0, 0, 0);
    }
}

// ---------------- stage A: AbT[kvi][e][t] = sum_d MbT[kv][e][d] * xb[t][d] ----------------
// grid.x = C * 96 ; block 256
__global__ __launch_bounds__(256, 2)
void k_gemm_A(const unsigned short* __restrict__ MbT, const unsigned short* __restrict__ xb,
              unsigned short* __restrict__ Ab, int kvLo) {
    __shared__ unsigned short As[128 * 64];
    __shared__ unsigned short Bs[128 * 64];
    int bid = blockIdx.x;
    int kvi = bid / 96; int rem = bid % 96;
    int et = rem / 16;   // M tile (e), 0..5
    int tt = rem % 16;   // N tile (t), 0..15
    int kv = kvLo + kvi;
    const unsigned short* Asrc = MbT + (size_t)kv * DDIM * DDIM + (size_t)(et * 128) * DDIM;
    const unsigned short* Bsrc = xb + (size_t)(tt * 128) * DDIM;
    unsigned short* Cdst = Ab + (size_t)kvi * DDIM * SEQ + (size_t)(et * 128) * SEQ + tt * 128;

    int tid = threadIdx.x;
    int lane = tid & 63, wave = tid >> 6;
    int wm = wave >> 1, wn = wave & 1;

    f32x4 acc[4][4];
#pragma unroll
    for (int i = 0; i < 4; ++i)
#pragma unroll
        for (int j = 0; j < 4; ++j) acc[i][j] = (f32x4){0.f, 0.f, 0.f, 0.f};

    for (int ks = 0; ks < DDIM / 64; ++ks) {
        int k0 = ks * 64;
        __syncthreads();
        stage_tile(Asrc + k0, DDIM, As, tid);
        stage_tile(Bsrc + k0, DDIM, Bs, tid);
        __syncthreads();
        mfma_tile(As, Bs, lane, wm, wn, acc);
    }

#pragma unroll
    for (int m = 0; m < 4; ++m) {
        int rb = wm * 64 + m * 16 + ((lane >> 4) << 2);
#pragma unroll
        for (int n = 0; n < 4; ++n) {
            int cb = wn * 64 + n * 16 + (lane & 15);
#pragma unroll
            for (int r = 0; r < 4; ++r)
                Cdst[(size_t)(rb + r) * SEQ + cb] = f2bf(acc[m][n][r]);
        }
    }
}

// ---------------- stage B: outz[zg][s][e] += sum_{kv in group} T_kv @ AbT_kv^T ----------------
// grid.x = (C/8) * 96 ; block 256
__global__ __launch_bounds__(256, 2)
void k_gemm_B(const unsigned short* __restrict__ Tmat, const unsigned short* __restrict__ Ab,
              float* __restrict__ outz, int kvLo) {
    __shared__ unsigned short As[128 * 64];
    __shared__ unsigned short Bs[128 * 64];
    int bid = blockIdx.x;
    int zl = bid / 96; int rem = bid % 96;
    int io = rem / 6; int et = rem % 6;
    int i = 15 - io;                // s-tile, heaviest first
    int zg = (kvLo >> 3) + zl;      // global z slice 0..5
    float* Cdst = outz + (size_t)zg * SEQ * DDIM + (size_t)(i * 128) * DDIM + et * 128;

    int tid = threadIdx.x;
    int lane = tid & 63, wave = tid >> 6;
    int wm = wave >> 1, wn = wave & 1;

    f32x4 acc[4][4];
#pragma unroll
    for (int m = 0; m < 4; ++m)
#pragma unroll
        for (int n = 0; n < 4; ++n) acc[m][n] = (f32x4){0.f, 0.f, 0.f, 0.f};

    for (int kvi8 = 0; kvi8 < 8; ++kvi8) {
        int kvi = zl * 8 + kvi8;
        const unsigned short* Abase = Tmat + (size_t)(kvLo + kvi) * 16 * 16384;
        const unsigned short* Bbase = Ab + (size_t)kvi * DDIM * SEQ + (size_t)(et * 128) * SEQ;
        for (int jj = 0; jj <= i; ++jj) {
            const unsigned short* Am = Abase + (size_t)(i - jj) * 16384;
#pragma unroll
            for (int h = 0; h < 2; ++h) {
                int k0 = h * 64;
                __syncthreads();
                stage_tile(Am + k0, 128, As, tid);
                stage_tile(Bbase + jj * 128 + k0, SEQ, Bs, tid);
                __syncthreads();
                mfma_tile(As, Bs, lane, wm, wn, acc);
            }
        }
    }

#pragma unroll
    for (int m = 0; m < 4; ++m) {
        int rb = wm * 64 + m * 16 + ((lane >> 4) << 2);
#pragma unroll
        for (int n = 0; n < 4; ++n) {
            int cb = wn * 64 + n * 16 + (lane & 15);
#pragma unroll
            for (int r = 0; r < 4; ++r)
                Cdst[(size_t)(rb + r) * DDIM + cb] = acc[m][n][r];
        }
    }
}

__global__ void k_reduce(const float* __restrict__ outz, float* __restrict__ out, int n) {
    int idx = blockIdx.x * blockDim.x + threadIdx.x;
    if (idx < n) {
        float s = 0.f;
#pragma unroll
        for (int z = 0; z < 6; ++z) s += outz[(size_t)z * n + idx];
        out[idx] = s;
    }
}

extern "C" void kernel_launch(void* const* d_in, const int* in_sizes, int n_in,
                              void* d_out, int out_size, void* d_ws, size_t ws_size,
                              hipStream_t stream) {
    (void)in_sizes; (void)n_in;
    const float* x   = (const float*)d_in[0];
    const float* phi = (const float*)d_in[1];
    const float* Mp  = (const float*)d_in[2];
    const float* Mm  = (const float*)d_in[3];
    float* out = (float*)d_out;

    char* ws = (char*)d_ws;
    size_t off = 0;
    auto alloc = [&](size_t bytes) { size_t o = off; off += (bytes + 255) & ~(size_t)255; return o; };
    size_t o_xb   = alloc((size_t)SEQ * DDIM * 2);
    size_t o_MbT  = alloc((size_t)NKV * DDIM * DDIM * 2);
    size_t o_T    = alloc((size_t)NKV * 16 * 128 * 128 * 2);
    size_t o_outz = alloc((size_t)6 * SEQ * DDIM * 4);
    size_t fixed = off;

    int C = 0;
    const int cand[4] = {48, 24, 16, 8};
    for (int ci = 0; ci < 4; ++ci) {
        if (fixed + (size_t)cand[ci] * DDIM * SEQ * 2 <= ws_size) { C = cand[ci]; break; }
    }
    if (C == 0) {  // workspace too small — fail cleanly (tells us ws_size is the issue)
        hipMemsetAsync(d_out, 0, (size_t)out_size * 4, stream);
        return;
    }
    size_t o_Ab = alloc((size_t)C * DDIM * SEQ * 2);

    unsigned short* xb   = (unsigned short*)(ws + o_xb);
    unsigned short* MbT  = (unsigned short*)(ws + o_MbT);
    unsigned short* Tmat = (unsigned short*)(ws + o_T);
    float*          outz = (float*)(ws + o_outz);
    unsigned short* Ab   = (unsigned short*)(ws + o_Ab);

    int n = SEQ * DDIM;
    k_cast_x<<<(n + 255) / 256, 256, 0, stream>>>(x, xb, n);
    k_transpose_M<<<NKV * 144, 256, 0, stream>>>(Mp, Mm, MbT);
    k_build_T<<<NKV * 16, 256, 0, stream>>>(phi, Tmat);

    for (int kvLo = 0; kvLo < NKV; kvLo += C) {
        k_gemm_A<<<C * 96, 256, 0, stream>>>(MbT, xb, Ab, kvLo);
        k_gemm_B<<<(C / 8) * 96, 256, 0, stream>>>(Tmat, Ab, outz, kvLo);
    }
    k_reduce<<<(n + 255) / 256, 256, 0, stream>>>(outz, out, n);
}

// Round 2
// 524.299 us; speedup vs baseline: 1.4875x; 1.4875x over previous
//
#include <hip/hip_runtime.h>
#include <hip/hip_bf16.h>
#include <stdint.h>

#define SEQ 2048
#define DDIM 768
#define KF 24
#define NKV 48
#define NSL 8   // outz accumulation slices

typedef unsigned short ushort_t;
typedef __attribute__((ext_vector_type(8))) short short8;
typedef __attribute__((ext_vector_type(4))) float f32x4;

typedef __attribute__((address_space(3))) uint32_t lds_u32;
typedef __attribute__((address_space(1))) uint32_t glb_u32;

__device__ __forceinline__ unsigned short f2bf(float f) {
    union { float f; uint32_t u; } v; v.f = f;
    uint32_t u = v.u;
    return (unsigned short)((u + 0x7fff + ((u >> 16) & 1)) >> 16);
}

// Image layout for a [128 rows][64 k] bf16 slab (16 KB), XOR-swizzled:
//   idx(row,k) = row*64 + (((k>>3) ^ (row&7))<<3) + (k&7)

// ---------------- prep: pack x ----------------
// xpk[tt][ks][img], row = t-local, k = d-local
__global__ void k_pack_x(const float* __restrict__ x, ushort_t* __restrict__ xpk) {
    int b = blockIdx.x;            // tt*12 + ks
    int tt = b / 12, ks = b % 12;
    int tid = threadIdx.x;
    ushort_t* dst = xpk + (size_t)b * 8192;
    const float* src = x + (size_t)tt * 128 * DDIM + ks * 64;
#pragma unroll
    for (int p = 0; p < 4; ++p) {
        int s = p * 256 + tid;
        int row = s >> 3, sl = s & 7;
        const float* rp = src + (size_t)row * DDIM + sl * 8;
        float4 a = *(const float4*)rp;
        float4 c = *(const float4*)(rp + 4);
        ushort_t v[8] = {f2bf(a.x), f2bf(a.y), f2bf(a.z), f2bf(a.w),
                         f2bf(c.x), f2bf(c.y), f2bf(c.z), f2bf(c.w)};
        *(uint4*)(dst + row * 64 + ((sl ^ (row & 7)) << 3)) = *(uint4*)v;
    }
}

// ---------------- prep: pack M transposed ----------------
// Mpk[kv][et][ks][img], row = e-local, k = d-local, value M_kv[d][e]
__global__ void k_pack_M(const float* __restrict__ Mp, const float* __restrict__ Mm,
                         ushort_t* __restrict__ Mpk) {
    __shared__ ushort_t lt[128 * 66];
    int b = blockIdx.x;            // (kv*6 + et)*12 + ks
    int kv = b / 72; int rem = b % 72; int et = rem / 12, ks = rem % 12;
    const float* src = ((kv < KF) ? Mp + (size_t)kv * DDIM * DDIM
                                  : Mm + (size_t)(kv - KF) * DDIM * DDIM)
                       + (size_t)(ks * 64) * DDIM + et * 128;
    int tid = threadIdx.x;
#pragma unroll
    for (int p = 0; p < 32; ++p) {
        int lin = p * 256 + tid;
        int d = lin >> 7, e = lin & 127;
        lt[e * 66 + d] = f2bf(src[(size_t)d * DDIM + e]);
    }
    __syncthreads();
    ushort_t* dst = Mpk + (size_t)b * 8192;
#pragma unroll
    for (int p = 0; p < 4; ++p) {
        int s = p * 256 + tid; int row = s >> 3, sl = s & 7;
        ushort_t v[8];
#pragma unroll
        for (int j = 0; j < 8; ++j) v[j] = lt[row * 66 + sl * 8 + j];
        *(uint4*)(dst + row * 64 + ((sl ^ (row & 7)) << 3)) = *(uint4*)v;
    }
}

// ---------------- prep: build Toeplitz blocks ----------------
// Tpk[kv][dm][h][img], row = a (s-local), k = b-local in half h
// value f_kv(128*dm + a - (h*64 + k)), zero for negative lag
__global__ void k_build_T(const float* __restrict__ phi, ushort_t* __restrict__ Tpk) {
    __shared__ float phiL[256];
    int b = blockIdx.x;            // kv*16 + dm
    int kv = b >> 4, dm = b & 15;
    int k = kv % KF; bool neg = kv >= KF;
    int tid = threadIdx.x;
    int tau = 128 * dm - 127 + tid;
    float v = 0.f;
    if (tid < 255 && tau >= 0 && tau < SEQ) {
        v = phi[(size_t)tau * KF + k];
        if (neg && (tau & 1)) v = -v;
    }
    phiL[tid] = v;
    __syncthreads();
    ushort_t* dst = Tpk + (size_t)b * 2 * 8192;
#pragma unroll
    for (int h = 0; h < 2; ++h) {
#pragma unroll
        for (int p = 0; p < 4; ++p) {
            int s = p * 256 + tid; int row = s >> 3, sl = s & 7;
            ushort_t v8[8];
#pragma unroll
            for (int j = 0; j < 8; ++j) {
                int col = h * 64 + sl * 8 + j;
                v8[j] = f2bf(phiL[row - col + 127]);
            }
            *(uint4*)(dst + h * 8192 + row * 64 + ((sl ^ (row & 7)) << 3)) = *(uint4*)v8;
        }
    }
}

// ---------------- GEMM helpers ----------------

// linear 16 KB image copy: global -> LDS via global_load_lds (16B/lane)
__device__ __forceinline__ void stage_img(const ushort_t* __restrict__ src,
                                          ushort_t* lds, int tid) {
    int wave = tid >> 6, lane = tid & 63;
    const char* s = (const char*)src + wave * 1024 + lane * 16;
    char* l = (char*)lds + wave * 1024;
#pragma unroll
    for (int p = 0; p < 4; ++p) {
        __builtin_amdgcn_global_load_lds((const glb_u32*)(s + p * 4096),
                                         (lds_u32*)(l + p * 4096), 16, 0, 0);
    }
}

__device__ __forceinline__ void mfma_img(const ushort_t* As, const ushort_t* Bs,
                                         int lane, int wm, int wn, f32x4 acc[4][4]) {
#pragma unroll
    for (int kk = 0; kk < 2; ++kk) {
        int slot = kk * 4 + (lane >> 4);
        short8 av[4], bv[4];
#pragma unroll
        for (int m = 0; m < 4; ++m) {
            int row = wm * 64 + m * 16 + (lane & 15);
            av[m] = *(const short8*)(As + row * 64 + ((slot ^ (row & 7)) << 3));
        }
#pragma unroll
        for (int n = 0; n < 4; ++n) {
            int row = wn * 64 + n * 16 + (lane & 15);
            bv[n] = *(const short8*)(Bs + row * 64 + ((slot ^ (row & 7)) << 3));
        }
#pragma unroll
        for (int m = 0; m < 4; ++m)
#pragma unroll
            for (int n = 0; n < 4; ++n)
                acc[m][n] = __builtin_amdgcn_mfma_f32_16x16x32_bf16(av[m], bv[n], acc[m][n], 0, 0, 0);
    }
}

// ---------------- stage A: Apk[kvi][et][tt][h][img] = (M_kv^T x^T) tile ----------------
__global__ __launch_bounds__(256, 3)
void k_gemm_A(const ushort_t* __restrict__ Mpk, const ushort_t* __restrict__ xpk,
              ushort_t* __restrict__ Apk, int kvLo) {
    __shared__ ushort_t smem[16384];
    ushort_t* As = smem; ushort_t* Bs = smem + 8192;
    int bid = blockIdx.x;
    int kvi = bid / 96; int rem = bid % 96; int et = rem / 16, tt = rem % 16;
    int kv = kvLo + kvi;
    const ushort_t* Asrc = Mpk + ((size_t)(kv * 6 + et) * 12) * 8192;
    const ushort_t* Bsrc = xpk + (size_t)(tt * 12) * 8192;
    int tid = threadIdx.x, lane = tid & 63, wave = tid >> 6;
    int wm = wave >> 1, wn = wave & 1;

    f32x4 acc[4][4];
#pragma unroll
    for (int m = 0; m < 4; ++m)
#pragma unroll
        for (int n = 0; n < 4; ++n) acc[m][n] = (f32x4){0.f, 0.f, 0.f, 0.f};

    for (int ks = 0; ks < 12; ++ks) {
        __syncthreads();
        stage_img(Asrc + ks * 8192, As, tid);
        stage_img(Bsrc + ks * 8192, Bs, tid);
        __syncthreads();
        mfma_img(As, Bs, lane, wm, wn, acc);
    }

    // repack C tile (rows=e, cols=t) into packed image pair in LDS, then stream out
    __syncthreads();
#pragma unroll
    for (int m = 0; m < 4; ++m) {
        int rb = wm * 64 + m * 16 + ((lane >> 4) << 2);
#pragma unroll
        for (int n = 0; n < 4; ++n) {
            int cb = wn * 64 + n * 16 + (lane & 15);
            int h = cb >> 6, c6 = cb & 63, sl = c6 >> 3, j = c6 & 7;
#pragma unroll
            for (int r = 0; r < 4; ++r) {
                int row = rb + r;
                smem[h * 8192 + row * 64 + ((sl ^ (row & 7)) << 3) + j] = f2bf(acc[m][n][r]);
            }
        }
    }
    __syncthreads();
    uint4* d4 = (uint4*)(Apk + ((size_t)((kvi * 6 + et) * 16 + tt) * 2) * 8192);
    const uint4* s4 = (const uint4*)smem;
#pragma unroll
    for (int p = 0; p < 8; ++p) d4[p * 256 + tid] = s4[p * 256 + tid];
}

// ---------------- stage B: outz[zl] (+)= sum_{kv in slice} T_kv @ A_kv ----------------
__global__ __launch_bounds__(256, 3)
void k_gemm_B(const ushort_t* __restrict__ Tpk, const ushort_t* __restrict__ Apk,
              float* __restrict__ outz, int kvLo, int ZKV, int accum) {
    __shared__ ushort_t smem[16384];
    ushort_t* As = smem; ushort_t* Bs = smem + 8192;
    int bid = blockIdx.x;
    int zl = bid / 96; int rem = bid % 96; int io = rem / 6, et = rem % 6;
    int i = 15 - io;   // heaviest s-tiles first
    int tid = threadIdx.x, lane = tid & 63, wave = tid >> 6;
    int wm = wave >> 1, wn = wave & 1;

    f32x4 acc[4][4];
#pragma unroll
    for (int m = 0; m < 4; ++m)
#pragma unroll
        for (int n = 0; n < 4; ++n) acc[m][n] = (f32x4){0.f, 0.f, 0.f, 0.f};

    for (int kvz = 0; kvz < ZKV; ++kvz) {
        int kvi = zl * ZKV + kvz;
        const ushort_t* Tbase = Tpk + (size_t)((kvLo + kvi) * 16) * 2 * 8192;
        const ushort_t* Bbase = Apk + (size_t)((kvi * 6 + et) * 16) * 2 * 8192;
        for (int jj = 0; jj <= i; ++jj) {
            const ushort_t* Am = Tbase + (size_t)(i - jj) * 2 * 8192;
            const ushort_t* Bm = Bbase + (size_t)jj * 2 * 8192;
#pragma unroll
            for (int h = 0; h < 2; ++h) {
                __syncthreads();
                stage_img(Am + h * 8192, As, tid);
                stage_img(Bm + h * 8192, Bs, tid);
                __syncthreads();
                mfma_img(As, Bs, lane, wm, wn, acc);
            }
        }
    }

    float* Cdst = outz + (size_t)zl * SEQ * DDIM + (size_t)(i * 128) * DDIM + et * 128;
#pragma unroll
    for (int m = 0; m < 4; ++m) {
        int rb = wm * 64 + m * 16 + ((lane >> 4) << 2);
#pragma unroll
        for (int n = 0; n < 4; ++n) {
            int cb = wn * 64 + n * 16 + (lane & 15);
#pragma unroll
            for (int r = 0; r < 4; ++r) {
                float* p = Cdst + (size_t)(rb + r) * DDIM + cb;
                float v = acc[m][n][r];
                if (accum) v += *p;
                *p = v;
            }
        }
    }
}

__global__ void k_reduce(const float* __restrict__ outz, float* __restrict__ out, int n4) {
    int idx = blockIdx.x * blockDim.x + threadIdx.x;
    if (idx < n4) {
        float4 s = ((const float4*)outz)[idx];
#pragma unroll
        for (int z = 1; z < NSL; ++z) {
            float4 t = ((const float4*)(outz + (size_t)z * SEQ * DDIM))[idx];
            s.x += t.x; s.y += t.y; s.z += t.z; s.w += t.w;
        }
        ((float4*)out)[idx] = s;
    }
}

extern "C" void kernel_launch(void* const* d_in, const int* in_sizes, int n_in,
                              void* d_out, int out_size, void* d_ws, size_t ws_size,
                              hipStream_t stream) {
    (void)in_sizes; (void)n_in;
    const float* x   = (const float*)d_in[0];
    const float* phi = (const float*)d_in[1];
    const float* Mp  = (const float*)d_in[2];
    const float* Mm  = (const float*)d_in[3];
    float* out = (float*)d_out;

    char* ws = (char*)d_ws;
    size_t off = 0;
    auto alloc = [&](size_t bytes) { size_t o = off; off += (bytes + 255) & ~(size_t)255; return o; };
    size_t o_xpk  = alloc((size_t)16 * 12 * 8192 * 2);
    size_t o_Mpk  = alloc((size_t)NKV * 6 * 12 * 8192 * 2);
    size_t o_Tpk  = alloc((size_t)NKV * 16 * 2 * 8192 * 2);
    size_t o_outz = alloc((size_t)NSL * SEQ * DDIM * 4);
    size_t fixed = off;

    int C = 0;
    const int cand[4] = {48, 24, 16, 8};
    for (int ci = 0; ci < 4; ++ci) {
        if (fixed + (size_t)cand[ci] * 6 * 16 * 2 * 8192 * 2 <= ws_size) { C = cand[ci]; break; }
    }
    if (C == 0) {
        hipMemsetAsync(d_out, 0, (size_t)out_size * 4, stream);
        return;
    }
    size_t o_Apk = alloc((size_t)C * 6 * 16 * 2 * 8192 * 2);
    int ZKV = C / NSL;

    ushort_t* xpk = (ushort_t*)(ws + o_xpk);
    ushort_t* Mpk = (ushort_t*)(ws + o_Mpk);
    ushort_t* Tpk = (ushort_t*)(ws + o_Tpk);
    float*    outz = (float*)(ws + o_outz);
    ushort_t* Apk = (ushort_t*)(ws + o_Apk);

    k_pack_x<<<16 * 12, 256, 0, stream>>>(x, xpk);
    k_pack_M<<<NKV * 6 * 12, 256, 0, stream>>>(Mp, Mm, Mpk);
    k_build_T<<<NKV * 16, 256, 0, stream>>>(phi, Tpk);

    int l = 0;
    for (int kvLo = 0; kvLo < NKV; kvLo += C, ++l) {
        k_gemm_A<<<C * 96, 256, 0, stream>>>(Mpk, xpk, Apk, kvLo);
        k_gemm_B<<<NSL * 96, 256, 0, stream>>>(Tpk, Apk, outz, kvLo, ZKV, l > 0);
    }
    int n4 = SEQ * DDIM / 4;
    k_reduce<<<(n4 + 255) / 256, 256, 0, stream>>>(outz, out, n4);
}

// Round 3
// 397.433 us; speedup vs baseline: 1.9623x; 1.3192x over previous
//
#include <hip/hip_runtime.h>
#include <hip/hip_bf16.h>
#include <stdint.h>

#define SEQ 2048
#define DDIM 768
#define KF 24
#define NKV 48
#define NZC 4   // outz split-K slices (jj-chunk index)

typedef unsigned short ushort_t;
typedef __attribute__((ext_vector_type(8))) short short8;
typedef __attribute__((ext_vector_type(4))) float f32x4;

typedef __attribute__((address_space(3))) uint32_t lds_u32;
typedef __attribute__((address_space(1))) uint32_t glb_u32;

__device__ __forceinline__ unsigned short f2bf(float f) {
    union { float f; uint32_t u; } v; v.f = f;
    uint32_t u = v.u;
    return (unsigned short)((u + 0x7fff + ((u >> 16) & 1)) >> 16);
}

// Image layout for a [128 rows][64 k] bf16 slab (16 KB), XOR-swizzled:
//   idx(row,k) = row*64 + (((k>>3) ^ (row&7))<<3) + (k&7)

// ---------------- prep: pack x ----------------
__global__ void k_pack_x(const float* __restrict__ x, ushort_t* __restrict__ xpk) {
    int b = blockIdx.x;            // tt*12 + ks
    int tt = b / 12, ks = b % 12;
    int tid = threadIdx.x;
    ushort_t* dst = xpk + (size_t)b * 8192;
    const float* src = x + (size_t)tt * 128 * DDIM + ks * 64;
#pragma unroll
    for (int p = 0; p < 4; ++p) {
        int s = p * 256 + tid;
        int row = s >> 3, sl = s & 7;
        const float* rp = src + (size_t)row * DDIM + sl * 8;
        float4 a = *(const float4*)rp;
        float4 c = *(const float4*)(rp + 4);
        ushort_t v[8] = {f2bf(a.x), f2bf(a.y), f2bf(a.z), f2bf(a.w),
                         f2bf(c.x), f2bf(c.y), f2bf(c.z), f2bf(c.w)};
        *(uint4*)(dst + row * 64 + ((sl ^ (row & 7)) << 3)) = *(uint4*)v;
    }
}

// ---------------- prep: pack M transposed ----------------
__global__ void k_pack_M(const float* __restrict__ Mp, const float* __restrict__ Mm,
                         ushort_t* __restrict__ Mpk) {
    __shared__ ushort_t lt[128 * 66];
    int b = blockIdx.x;            // (kv*6 + et)*12 + ks
    int kv = b / 72; int rem = b % 72; int et = rem / 12, ks = rem % 12;
    const float* src = ((kv < KF) ? Mp + (size_t)kv * DDIM * DDIM
                                  : Mm + (size_t)(kv - KF) * DDIM * DDIM)
                       + (size_t)(ks * 64) * DDIM + et * 128;
    int tid = threadIdx.x;
#pragma unroll
    for (int p = 0; p < 32; ++p) {
        int lin = p * 256 + tid;
        int d = lin >> 7, e = lin & 127;
        lt[e * 66 + d] = f2bf(src[(size_t)d * DDIM + e]);
    }
    __syncthreads();
    ushort_t* dst = Mpk + (size_t)b * 8192;
#pragma unroll
    for (int p = 0; p < 4; ++p) {
        int s = p * 256 + tid; int row = s >> 3, sl = s & 7;
        ushort_t v[8];
#pragma unroll
        for (int j = 0; j < 8; ++j) v[j] = lt[row * 66 + sl * 8 + j];
        *(uint4*)(dst + row * 64 + ((sl ^ (row & 7)) << 3)) = *(uint4*)v;
    }
}

// ---------------- prep: build Toeplitz blocks ----------------
__global__ void k_build_T(const float* __restrict__ phi, ushort_t* __restrict__ Tpk) {
    __shared__ float phiL[256];
    int b = blockIdx.x;            // kv*16 + lag
    int kv = b >> 4, dm = b & 15;
    int k = kv % KF; bool neg = kv >= KF;
    int tid = threadIdx.x;
    int tau = 128 * dm - 127 + tid;
    float v = 0.f;
    if (tid < 255 && tau >= 0 && tau < SEQ) {
        v = phi[(size_t)tau * KF + k];
        if (neg && (tau & 1)) v = -v;
    }
    phiL[tid] = v;
    __syncthreads();
    ushort_t* dst = Tpk + (size_t)b * 2 * 8192;
#pragma unroll
    for (int h = 0; h < 2; ++h) {
#pragma unroll
        for (int p = 0; p < 4; ++p) {
            int s = p * 256 + tid; int row = s >> 3, sl = s & 7;
            ushort_t v8[8];
#pragma unroll
            for (int j = 0; j < 8; ++j) {
                int col = h * 64 + sl * 8 + j;
                v8[j] = f2bf(phiL[row - col + 127]);
            }
            *(uint4*)(dst + h * 8192 + row * 64 + ((sl ^ (row & 7)) << 3)) = *(uint4*)v8;
        }
    }
}

// ---------------- gemm_A helpers (proven r2 structure) ----------------

__device__ __forceinline__ void stage_img(const ushort_t* __restrict__ src,
                                          ushort_t* lds, int tid) {
    int wave = tid >> 6, lane = tid & 63;
    const char* s = (const char*)src + wave * 1024 + lane * 16;
    char* l = (char*)lds + wave * 1024;
#pragma unroll
    for (int p = 0; p < 4; ++p) {
        __builtin_amdgcn_global_load_lds((const glb_u32*)(s + p * 4096),
                                         (lds_u32*)(l + p * 4096), 16, 0, 0);
    }
}

__device__ __forceinline__ void mfma_img(const ushort_t* As, const ushort_t* Bs,
                                         int lane, int wm, int wn, f32x4 acc[4][4]) {
#pragma unroll
    for (int kk = 0; kk < 2; ++kk) {
        int slot = kk * 4 + (lane >> 4);
        short8 av[4], bv[4];
#pragma unroll
        for (int m = 0; m < 4; ++m) {
            int row = wm * 64 + m * 16 + (lane & 15);
            av[m] = *(const short8*)(As + row * 64 + ((slot ^ (row & 7)) << 3));
        }
#pragma unroll
        for (int n = 0; n < 4; ++n) {
            int row = wn * 64 + n * 16 + (lane & 15);
            bv[n] = *(const short8*)(Bs + row * 64 + ((slot ^ (row & 7)) << 3));
        }
#pragma unroll
        for (int m = 0; m < 4; ++m)
#pragma unroll
            for (int n = 0; n < 4; ++n)
                acc[m][n] = __builtin_amdgcn_mfma_f32_16x16x32_bf16(av[m], bv[n], acc[m][n], 0, 0, 0);
    }
}

// ---------------- stage A (unchanged r2): Apk[kvi][et][tt][h][img] ----------------
__global__ __launch_bounds__(256, 3)
void k_gemm_A(const ushort_t* __restrict__ Mpk, const ushort_t* __restrict__ xpk,
              ushort_t* __restrict__ Apk, int kvLo) {
    __shared__ ushort_t smem[16384];
    ushort_t* As = smem; ushort_t* Bs = smem + 8192;
    int bid = blockIdx.x;
    int kvi = bid / 96; int rem = bid % 96; int et = rem / 16, tt = rem % 16;
    int kv = kvLo + kvi;
    const ushort_t* Asrc = Mpk + ((size_t)(kv * 6 + et) * 12) * 8192;
    const ushort_t* Bsrc = xpk + (size_t)(tt * 12) * 8192;
    int tid = threadIdx.x, lane = tid & 63, wave = tid >> 6;
    int wm = wave >> 1, wn = wave & 1;

    f32x4 acc[4][4];
#pragma unroll
    for (int m = 0; m < 4; ++m)
#pragma unroll
        for (int n = 0; n < 4; ++n) acc[m][n] = (f32x4){0.f, 0.f, 0.f, 0.f};

    for (int ks = 0; ks < 12; ++ks) {
        __syncthreads();
        stage_img(Asrc + ks * 8192, As, tid);
        stage_img(Bsrc + ks * 8192, Bs, tid);
        __syncthreads();
        mfma_img(As, Bs, lane, wm, wn, acc);
    }

    __syncthreads();
#pragma unroll
    for (int m = 0; m < 4; ++m) {
        int rb = wm * 64 + m * 16 + ((lane >> 4) << 2);
#pragma unroll
        for (int n = 0; n < 4; ++n) {
            int cb = wn * 64 + n * 16 + (lane & 15);
            int h = cb >> 6, c6 = cb & 63, sl = c6 >> 3, j = c6 & 7;
#pragma unroll
            for (int r = 0; r < 4; ++r) {
                int row = rb + r;
                smem[h * 8192 + row * 64 + ((sl ^ (row & 7)) << 3) + j] = f2bf(acc[m][n][r]);
            }
        }
    }
    __syncthreads();
    uint4* d4 = (uint4*)(Apk + ((size_t)((kvi * 6 + et) * 16 + tt) * 2) * 8192);
    const uint4* s4 = (const uint4*)smem;
#pragma unroll
    for (int p = 0; p < 8; ++p) d4[p * 256 + tid] = s4[p * 256 + tid];
}

// ---------------- stage B v3: pipelined counted-vmcnt template ----------------
// Work unit: out tile (i1 in 0..15, et in 0..5), jj-chunk zc of <=4 jj values.
// 40 (i1,zc) combos * 6 et = 240 blocks, all co-resident. outz[zc] accumulated.
__global__ __launch_bounds__(512, 2)
void k_gemm_Bv3(const ushort_t* __restrict__ Tpk, const ushort_t* __restrict__ Apk,
                float* __restrict__ outz, int kvLo, int nkv) {
    __shared__ ushort_t smem[2][2][8192];   // [buf][op: 0=T(A-side),1=A(B-side)]

    // chunked XCD swizzle: physical bid -> logical lid so each XCD gets a
    // contiguous run of 30 logical blocks (shared et panels stay in its L2)
    int bid = blockIdx.x;
    int lid = (bid & 7) * 30 + (bid >> 3);
    int et = lid / 40;
    int cidx = lid % 40;
    int i1 = 0, zc = 0, base = 0;
    for (int t = 0; t < 16; ++t) {
        int nc = (t >> 2) + 1;
        if (cidx < base + nc) { i1 = t; zc = cidx - base; break; }
        base += nc;
    }
    int jlo = zc * 4;
    int jhi = (jlo + 3 < i1) ? (jlo + 3) : i1;
    int NS = nkv * (jhi - jlo + 1) * 2;

    int tid = threadIdx.x, lane = tid & 63, wave = tid >> 6;
    int wm = wave >> 2, wn = wave & 3;

    // per-wave staging: each wave copies 2 KB of each 16 KB image (2 instrs)
    const char* lanes_off = (const char*)0;  // silence unused warnings
    (void)lanes_off;

    f32x4 acc[4][2];
#pragma unroll
    for (int m = 0; m < 4; ++m)
#pragma unroll
        for (int n = 0; n < 2; ++n) acc[m][n] = (f32x4){0.f, 0.f, 0.f, 0.f};

    auto timg = [&](int kv, int jj, int h) -> const ushort_t* {
        return Tpk + ((size_t)(((kvLo + kv) * 16 + (i1 - jj)) * 2 + h)) * 8192;
    };
    auto aimg = [&](int kv, int jj, int h) -> const ushort_t* {
        return Apk + ((size_t)(((kv * 6 + et) * 16 + jj) * 2 + h)) * 8192;
    };
    auto stage2 = [&](const ushort_t* src, ushort_t* dst) {
        const char* s = (const char*)src + wave * 2048 + lane * 16;
        char* l = (char*)dst + wave * 2048;
        __builtin_amdgcn_global_load_lds((const glb_u32*)s, (lds_u32*)l, 16, 0, 0);
        __builtin_amdgcn_global_load_lds((const glb_u32*)(s + 1024), (lds_u32*)(l + 1024), 16, 0, 0);
    };

    int kv = 0, jj = jlo, h = 0;
    // prologue: stage step 0 into buf 0 (4 loads/wave outstanding)
    stage2(timg(kv, jj, h), smem[0][0]);
    stage2(aimg(kv, jj, h), smem[0][1]);

    for (int s = 0; s < NS; ++s) {
        int c = s & 1;
        // next-step coords
        int nh = h ^ 1, njj = jj, nkvv = kv;
        if (!nh) { njj = jj + 1; if (njj > jhi) { njj = jlo; nkvv = kv + 1; } }
        bool more = (s + 1 < NS);

        // issue next T-image into the buffer whose reads retired last step
        if (more) {
            stage2(timg(nkvv, njj, nh), smem[c ^ 1][0]);
            asm volatile("s_waitcnt vmcnt(2)" ::: "memory");   // this step's 4 landed
        } else {
            asm volatile("s_waitcnt vmcnt(0)" ::: "memory");
        }
        __builtin_amdgcn_s_barrier();          // gate: all waves' data landed
        __builtin_amdgcn_sched_barrier(0);

        const ushort_t* As = smem[c][0];
        const ushort_t* Bs = smem[c][1];
        short8 av[2][4], bv[2][2];
#pragma unroll
        for (int kk = 0; kk < 2; ++kk) {
            int slot = kk * 4 + (lane >> 4);
#pragma unroll
            for (int m = 0; m < 4; ++m) {
                int row = wm * 64 + m * 16 + (lane & 15);
                av[kk][m] = *(const short8*)(As + row * 64 + ((slot ^ (row & 7)) << 3));
            }
#pragma unroll
            for (int n = 0; n < 2; ++n) {
                int row = wn * 32 + n * 16 + (lane & 15);
                bv[kk][n] = *(const short8*)(Bs + row * 64 + ((slot ^ (row & 7)) << 3));
            }
        }
        if (more) stage2(aimg(nkvv, njj, nh), smem[c ^ 1][1]);

        asm volatile("s_waitcnt lgkmcnt(0)" ::: "memory");     // my ds_reads done
        __builtin_amdgcn_sched_barrier(0);                     // rule 18

        __builtin_amdgcn_s_setprio(1);
#pragma unroll
        for (int kk = 0; kk < 2; ++kk)
#pragma unroll
            for (int m = 0; m < 4; ++m)
#pragma unroll
                for (int n = 0; n < 2; ++n)
                    acc[m][n] = __builtin_amdgcn_mfma_f32_16x16x32_bf16(av[kk][m], bv[kk][n], acc[m][n], 0, 0, 0);
        __builtin_amdgcn_s_setprio(0);
        __builtin_amdgcn_s_barrier();          // retire this step's ds_reads
        kv = nkvv; jj = njj; h = nh;
    }

    // epilogue: accumulate into outz[zc] (pre-zeroed by memset)
    float* dst = outz + ((size_t)zc * SEQ + (size_t)i1 * 128) * DDIM + et * 128;
#pragma unroll
    for (int m = 0; m < 4; ++m) {
        int rb = wm * 64 + m * 16 + ((lane >> 4) << 2);
#pragma unroll
        for (int n = 0; n < 2; ++n) {
            int cb = wn * 32 + n * 16 + (lane & 15);
#pragma unroll
            for (int r = 0; r < 4; ++r) {
                float* p = dst + (size_t)(rb + r) * DDIM + cb;
                *p += acc[m][n][r];
            }
        }
    }
}

__global__ void k_reduce(const float* __restrict__ outz, float* __restrict__ out, int n4) {
    int idx = blockIdx.x * blockDim.x + threadIdx.x;
    if (idx < n4) {
        float4 s = ((const float4*)outz)[idx];
#pragma unroll
        for (int z = 1; z < NZC; ++z) {
            float4 t = ((const float4*)(outz + (size_t)z * SEQ * DDIM))[idx];
            s.x += t.x; s.y += t.y; s.z += t.z; s.w += t.w;
        }
        ((float4*)out)[idx] = s;
    }
}

extern "C" void kernel_launch(void* const* d_in, const int* in_sizes, int n_in,
                              void* d_out, int out_size, void* d_ws, size_t ws_size,
                              hipStream_t stream) {
    (void)in_sizes; (void)n_in;
    const float* x   = (const float*)d_in[0];
    const float* phi = (const float*)d_in[1];
    const float* Mp  = (const float*)d_in[2];
    const float* Mm  = (const float*)d_in[3];
    float* out = (float*)d_out;

    char* ws = (char*)d_ws;
    size_t off = 0;
    auto alloc = [&](size_t bytes) { size_t o = off; off += (bytes + 255) & ~(size_t)255; return o; };
    size_t o_xpk  = alloc((size_t)16 * 12 * 8192 * 2);
    size_t o_Mpk  = alloc((size_t)NKV * 6 * 12 * 8192 * 2);
    size_t o_Tpk  = alloc((size_t)NKV * 16 * 2 * 8192 * 2);
    size_t o_outz = alloc((size_t)NZC * SEQ * DDIM * 4);
    size_t fixed = off;

    int C = 0;
    const int cand[4] = {48, 24, 16, 8};
    for (int ci = 0; ci < 4; ++ci) {
        if (fixed + (size_t)cand[ci] * 6 * 16 * 2 * 8192 * 2 <= ws_size) { C = cand[ci]; break; }
    }
    if (C == 0) {
        hipMemsetAsync(d_out, 0, (size_t)out_size * 4, stream);
        return;
    }
    size_t o_Apk = alloc((size_t)C * 6 * 16 * 2 * 8192 * 2);

    ushort_t* xpk = (ushort_t*)(ws + o_xpk);
    ushort_t* Mpk = (ushort_t*)(ws + o_Mpk);
    ushort_t* Tpk = (ushort_t*)(ws + o_Tpk);
    float*    outz = (float*)(ws + o_outz);
    ushort_t* Apk = (ushort_t*)(ws + o_Apk);

    k_pack_x<<<16 * 12, 256, 0, stream>>>(x, xpk);
    k_pack_M<<<NKV * 6 * 12, 256, 0, stream>>>(Mp, Mm, Mpk);
    k_build_T<<<NKV * 16, 256, 0, stream>>>(phi, Tpk);
    hipMemsetAsync(outz, 0, (size_t)NZC * SEQ * DDIM * 4, stream);

    for (int kvLo = 0; kvLo < NKV; kvLo += C) {
        k_gemm_A<<<C * 96, 256, 0, stream>>>(Mpk, xpk, Apk, kvLo);
        k_gemm_Bv3<<<240, 512, 0, stream>>>(Tpk, Apk, outz, kvLo, C);
    }
    int n4 = SEQ * DDIM / 4;
    k_reduce<<<(n4 + 255) / 256, 256, 0, stream>>>(outz, out, n4);
}

// Round 4
// 363.133 us; speedup vs baseline: 2.1476x; 1.0945x over previous
//
#include <hip/hip_runtime.h>
#include <hip/hip_bf16.h>
#include <stdint.h>

#define SEQ 2048
#define DDIM 768
#define KF 24
#define NKV 48
#define NZC 8   // outz split-K slices (jj-chunk of 2)

typedef unsigned short ushort_t;
typedef __attribute__((ext_vector_type(8))) short short8;
typedef __attribute__((ext_vector_type(4))) float f32x4;

typedef __attribute__((address_space(3))) uint32_t lds_u32;
typedef __attribute__((address_space(1))) uint32_t glb_u32;

__device__ __forceinline__ unsigned short f2bf(float f) {
    union { float f; uint32_t u; } v; v.f = f;
    uint32_t u = v.u;
    return (unsigned short)((u + 0x7fff + ((u >> 16) & 1)) >> 16);
}

// Image layout for a [128 rows][64 k] bf16 slab (16 KB), XOR-swizzled:
//   idx(row,k) = row*64 + (((k>>3) ^ (row&7))<<3) + (k&7)

// ---------------- prep: pack x ----------------
__global__ void k_pack_x(const float* __restrict__ x, ushort_t* __restrict__ xpk) {
    int b = blockIdx.x;            // tt*12 + ks
    int tt = b / 12, ks = b % 12;
    int tid = threadIdx.x;
    ushort_t* dst = xpk + (size_t)b * 8192;
    const float* src = x + (size_t)tt * 128 * DDIM + ks * 64;
#pragma unroll
    for (int p = 0; p < 4; ++p) {
        int s = p * 256 + tid;
        int row = s >> 3, sl = s & 7;
        const float* rp = src + (size_t)row * DDIM + sl * 8;
        float4 a = *(const float4*)rp;
        float4 c = *(const float4*)(rp + 4);
        ushort_t v[8] = {f2bf(a.x), f2bf(a.y), f2bf(a.z), f2bf(a.w),
                         f2bf(c.x), f2bf(c.y), f2bf(c.z), f2bf(c.w)};
        *(uint4*)(dst + row * 64 + ((sl ^ (row & 7)) << 3)) = *(uint4*)v;
    }
}

// ---------------- prep: pack M transposed ----------------
__global__ void k_pack_M(const float* __restrict__ Mp, const float* __restrict__ Mm,
                         ushort_t* __restrict__ Mpk) {
    __shared__ ushort_t lt[128 * 66];
    int b = blockIdx.x;            // (kv*6 + et)*12 + ks
    int kv = b / 72; int rem = b % 72; int et = rem / 12, ks = rem % 12;
    const float* src = ((kv < KF) ? Mp + (size_t)kv * DDIM * DDIM
                                  : Mm + (size_t)(kv - KF) * DDIM * DDIM)
                       + (size_t)(ks * 64) * DDIM + et * 128;
    int tid = threadIdx.x;
#pragma unroll
    for (int p = 0; p < 32; ++p) {
        int lin = p * 256 + tid;
        int d = lin >> 7, e = lin & 127;
        lt[e * 66 + d] = f2bf(src[(size_t)d * DDIM + e]);
    }
    __syncthreads();
    ushort_t* dst = Mpk + (size_t)b * 8192;
#pragma unroll
    for (int p = 0; p < 4; ++p) {
        int s = p * 256 + tid; int row = s >> 3, sl = s & 7;
        ushort_t v[8];
#pragma unroll
        for (int j = 0; j < 8; ++j) v[j] = lt[row * 66 + sl * 8 + j];
        *(uint4*)(dst + row * 64 + ((sl ^ (row & 7)) << 3)) = *(uint4*)v;
    }
}

// ---------------- prep: build Toeplitz blocks ----------------
__global__ void k_build_T(const float* __restrict__ phi, ushort_t* __restrict__ Tpk) {
    __shared__ float phiL[256];
    int b = blockIdx.x;            // kv*16 + lag
    int kv = b >> 4, dm = b & 15;
    int k = kv % KF; bool neg = kv >= KF;
    int tid = threadIdx.x;
    int tau = 128 * dm - 127 + tid;
    float v = 0.f;
    if (tid < 255 && tau >= 0 && tau < SEQ) {
        v = phi[(size_t)tau * KF + k];
        if (neg && (tau & 1)) v = -v;
    }
    phiL[tid] = v;
    __syncthreads();
    ushort_t* dst = Tpk + (size_t)b * 2 * 8192;
#pragma unroll
    for (int h = 0; h < 2; ++h) {
#pragma unroll
        for (int p = 0; p < 4; ++p) {
            int s = p * 256 + tid; int row = s >> 3, sl = s & 7;
            ushort_t v8[8];
#pragma unroll
            for (int j = 0; j < 8; ++j) {
                int col = h * 64 + sl * 8 + j;
                v8[j] = f2bf(phiL[row - col + 127]);
            }
            *(uint4*)(dst + h * 8192 + row * 64 + ((sl ^ (row & 7)) << 3)) = *(uint4*)v8;
        }
    }
}

// ---------------- gemm_A helpers (proven r2/r3 structure) ----------------

__device__ __forceinline__ void stage_img(const ushort_t* __restrict__ src,
                                          ushort_t* lds, int tid) {
    int wave = tid >> 6, lane = tid & 63;
    const char* s = (const char*)src + wave * 1024 + lane * 16;
    char* l = (char*)lds + wave * 1024;
#pragma unroll
    for (int p = 0; p < 4; ++p) {
        __builtin_amdgcn_global_load_lds((const glb_u32*)(s + p * 4096),
                                         (lds_u32*)(l + p * 4096), 16, 0, 0);
    }
}

__device__ __forceinline__ void mfma_img(const ushort_t* As, const ushort_t* Bs,
                                         int lane, int wm, int wn, f32x4 acc[4][4]) {
#pragma unroll
    for (int kk = 0; kk < 2; ++kk) {
        int slot = kk * 4 + (lane >> 4);
        short8 av[4], bv[4];
#pragma unroll
        for (int m = 0; m < 4; ++m) {
            int row = wm * 64 + m * 16 + (lane & 15);
            av[m] = *(const short8*)(As + row * 64 + ((slot ^ (row & 7)) << 3));
        }
#pragma unroll
        for (int n = 0; n < 4; ++n) {
            int row = wn * 64 + n * 16 + (lane & 15);
            bv[n] = *(const short8*)(Bs + row * 64 + ((slot ^ (row & 7)) << 3));
        }
#pragma unroll
        for (int m = 0; m < 4; ++m)
#pragma unroll
            for (int n = 0; n < 4; ++n)
                acc[m][n] = __builtin_amdgcn_mfma_f32_16x16x32_bf16(av[m], bv[n], acc[m][n], 0, 0, 0);
    }
}

// ---------------- stage A (unchanged r3): Apk[kvi][et][tt][h][img] ----------------
__global__ __launch_bounds__(256, 3)
void k_gemm_A(const ushort_t* __restrict__ Mpk, const ushort_t* __restrict__ xpk,
              ushort_t* __restrict__ Apk, int kvLo) {
    __shared__ ushort_t smem[16384];
    ushort_t* As = smem; ushort_t* Bs = smem + 8192;
    int bid = blockIdx.x;
    int kvi = bid / 96; int rem = bid % 96; int et = rem / 16, tt = rem % 16;
    int kv = kvLo + kvi;
    const ushort_t* Asrc = Mpk + ((size_t)(kv * 6 + et) * 12) * 8192;
    const ushort_t* Bsrc = xpk + (size_t)(tt * 12) * 8192;
    int tid = threadIdx.x, lane = tid & 63, wave = tid >> 6;
    int wm = wave >> 1, wn = wave & 1;

    f32x4 acc[4][4];
#pragma unroll
    for (int m = 0; m < 4; ++m)
#pragma unroll
        for (int n = 0; n < 4; ++n) acc[m][n] = (f32x4){0.f, 0.f, 0.f, 0.f};

    for (int ks = 0; ks < 12; ++ks) {
        __syncthreads();
        stage_img(Asrc + ks * 8192, As, tid);
        stage_img(Bsrc + ks * 8192, Bs, tid);
        __syncthreads();
        mfma_img(As, Bs, lane, wm, wn, acc);
    }

    __syncthreads();
#pragma unroll
    for (int m = 0; m < 4; ++m) {
        int rb = wm * 64 + m * 16 + ((lane >> 4) << 2);
#pragma unroll
        for (int n = 0; n < 4; ++n) {
            int cb = wn * 64 + n * 16 + (lane & 15);
            int h = cb >> 6, c6 = cb & 63, sl = c6 >> 3, j = c6 & 7;
#pragma unroll
            for (int r = 0; r < 4; ++r) {
                int row = rb + r;
                smem[h * 8192 + row * 64 + ((sl ^ (row & 7)) << 3) + j] = f2bf(acc[m][n][r]);
            }
        }
    }
    __syncthreads();
    uint4* d4 = (uint4*)(Apk + ((size_t)((kvi * 6 + et) * 16 + tt) * 2) * 8192);
    const uint4* s4 = (const uint4*)smem;
#pragma unroll
    for (int p = 0; p < 8; ++p) d4[p * 256 + tid] = s4[p * 256 + tid];
}

// ---------------- stage B v4: 256-thr, 2 blocks/CU, wave 64x64, counted vmcnt ----------------
// Work unit: (i1, et, zc) with jj in [2*zc, min(2*zc+1, i1)].
// Grid = 6 et * 72 chunks = 432 blocks, 64 KB LDS -> 2 blocks/CU.
__global__ __launch_bounds__(256, 2)
void k_gemm_Bv4(const ushort_t* __restrict__ Tpk, const ushort_t* __restrict__ Apk,
                float* __restrict__ outz, int kvLo, int nkv) {
    __shared__ ushort_t smem[2][2][8192];   // [buf][0=T, 1=A]

    // bijective XCD swizzle: 432 = 8 * 54
    int bid = blockIdx.x;
    int lid = (bid & 7) * 54 + (bid >> 3);
    int et = lid / 72;
    int cidx = lid % 72;
    int i1 = 0, zc = 0, base = 0;
#pragma unroll
    for (int t = 0; t < 16; ++t) {          // heaviest i1 first
        int cand = 15 - t;
        int nc = (cand >> 1) + 1;
        if (cidx < base + nc) { i1 = cand; zc = cidx - base; break; }
        base += nc;
    }
    int jlo = zc * 2;
    int jhi = (jlo + 1 < i1) ? (jlo + 1) : i1;
    int NS = nkv * (jhi - jlo + 1) * 2;

    int tid = threadIdx.x, lane = tid & 63, wave = tid >> 6;
    int wm = wave >> 1, wn = wave & 1;

    f32x4 acc[4][4];
#pragma unroll
    for (int m = 0; m < 4; ++m)
#pragma unroll
        for (int n = 0; n < 4; ++n) acc[m][n] = (f32x4){0.f, 0.f, 0.f, 0.f};

    auto timg = [&](int kv, int jj, int h) -> const ushort_t* {
        return Tpk + ((size_t)(((kvLo + kv) * 16 + (i1 - jj)) * 2 + h)) * 8192;
    };
    auto aimg = [&](int kv, int jj, int h) -> const ushort_t* {
        return Apk + ((size_t)(((kv * 6 + et) * 16 + jj) * 2 + h)) * 8192;
    };
    // 4 waves: each wave stages 4 KB of the 16 KB image (4 instrs)
    auto stage4 = [&](const ushort_t* src, ushort_t* dst) {
        const char* s = (const char*)src + wave * 4096 + lane * 16;
        char* l = (char*)dst + wave * 4096;
#pragma unroll
        for (int p = 0; p < 4; ++p)
            __builtin_amdgcn_global_load_lds((const glb_u32*)(s + p * 1024),
                                             (lds_u32*)(l + p * 1024), 16, 0, 0);
    };

    int kv = 0, jj = jlo, h = 0;
    stage4(timg(kv, jj, h), smem[0][0]);
    stage4(aimg(kv, jj, h), smem[0][1]);

    for (int s = 0; s < NS; ++s) {
        int c = s & 1;
        int nh = h ^ 1, njj = jj, nkvv = kv;
        if (!nh) { njj = jj + 1; if (njj > jhi) { njj = jlo; nkvv = kv + 1; } }
        bool more = (s + 1 < NS);

        if (more) {
            stage4(timg(nkvv, njj, nh), smem[c ^ 1][0]);
            asm volatile("s_waitcnt vmcnt(4)" ::: "memory");   // this step's 8 landed
        } else {
            asm volatile("s_waitcnt vmcnt(0)" ::: "memory");
        }
        __builtin_amdgcn_s_barrier();
        __builtin_amdgcn_sched_barrier(0);

        const ushort_t* As = smem[c][0];
        const ushort_t* Bs = smem[c][1];
        short8 av[2][4], bv[2][4];
#pragma unroll
        for (int kk = 0; kk < 2; ++kk) {
            int slot = kk * 4 + (lane >> 4);
#pragma unroll
            for (int m = 0; m < 4; ++m) {
                int row = wm * 64 + m * 16 + (lane & 15);
                av[kk][m] = *(const short8*)(As + row * 64 + ((slot ^ (row & 7)) << 3));
            }
#pragma unroll
            for (int n = 0; n < 4; ++n) {
                int row = wn * 64 + n * 16 + (lane & 15);
                bv[kk][n] = *(const short8*)(Bs + row * 64 + ((slot ^ (row & 7)) << 3));
            }
        }
        if (more) stage4(aimg(nkvv, njj, nh), smem[c ^ 1][1]);

        asm volatile("s_waitcnt lgkmcnt(0)" ::: "memory");
        __builtin_amdgcn_sched_barrier(0);

        __builtin_amdgcn_s_setprio(1);
#pragma unroll
        for (int kk = 0; kk < 2; ++kk)
#pragma unroll
            for (int m = 0; m < 4; ++m)
#pragma unroll
                for (int n = 0; n < 4; ++n)
                    acc[m][n] = __builtin_amdgcn_mfma_f32_16x16x32_bf16(av[kk][m], bv[kk][n], acc[m][n], 0, 0, 0);
        __builtin_amdgcn_s_setprio(0);
        __builtin_amdgcn_s_barrier();
        kv = nkvv; jj = njj; h = nh;
    }

    float* dst = outz + ((size_t)zc * SEQ + (size_t)i1 * 128) * DDIM + et * 128;
#pragma unroll
    for (int m = 0; m < 4; ++m) {
        int rb = wm * 64 + m * 16 + ((lane >> 4) << 2);
#pragma unroll
        for (int n = 0; n < 4; ++n) {
            int cb = wn * 64 + n * 16 + (lane & 15);
#pragma unroll
            for (int r = 0; r < 4; ++r) {
                float* p = dst + (size_t)(rb + r) * DDIM + cb;
                *p += acc[m][n][r];
            }
        }
    }
}

__global__ void k_reduce(const float* __restrict__ outz, float* __restrict__ out, int n4) {
    int idx = blockIdx.x * blockDim.x + threadIdx.x;
    if (idx < n4) {
        float4 s = ((const float4*)outz)[idx];
#pragma unroll
        for (int z = 1; z < NZC; ++z) {
            float4 t = ((const float4*)(outz + (size_t)z * SEQ * DDIM))[idx];
            s.x += t.x; s.y += t.y; s.z += t.z; s.w += t.w;
        }
        ((float4*)out)[idx] = s;
    }
}

extern "C" void kernel_launch(void* const* d_in, const int* in_sizes, int n_in,
                              void* d_out, int out_size, void* d_ws, size_t ws_size,
                              hipStream_t stream) {
    (void)in_sizes; (void)n_in;
    const float* x   = (const float*)d_in[0];
    const float* phi = (const float*)d_in[1];
    const float* Mp  = (const float*)d_in[2];
    const float* Mm  = (const float*)d_in[3];
    float* out = (float*)d_out;

    char* ws = (char*)d_ws;
    size_t off = 0;
    auto alloc = [&](size_t bytes) { size_t o = off; off += (bytes + 255) & ~(size_t)255; return o; };
    size_t o_xpk  = alloc((size_t)16 * 12 * 8192 * 2);
    size_t o_Mpk  = alloc((size_t)NKV * 6 * 12 * 8192 * 2);
    size_t o_Tpk  = alloc((size_t)NKV * 16 * 2 * 8192 * 2);
    size_t o_outz = alloc((size_t)NZC * SEQ * DDIM * 4);
    size_t fixed = off;

    int C = 0;
    const int cand[4] = {48, 24, 16, 8};
    for (int ci = 0; ci < 4; ++ci) {
        if (fixed + (size_t)cand[ci] * 6 * 16 * 2 * 8192 * 2 <= ws_size) { C = cand[ci]; break; }
    }
    if (C == 0) {
        hipMemsetAsync(d_out, 0, (size_t)out_size * 4, stream);
        return;
    }
    size_t o_Apk = alloc((size_t)C * 6 * 16 * 2 * 8192 * 2);

    ushort_t* xpk = (ushort_t*)(ws + o_xpk);
    ushort_t* Mpk = (ushort_t*)(ws + o_Mpk);
    ushort_t* Tpk = (ushort_t*)(ws + o_Tpk);
    float*    outz = (float*)(ws + o_outz);
    ushort_t* Apk = (ushort_t*)(ws + o_Apk);

    k_pack_x<<<16 * 12, 256, 0, stream>>>(x, xpk);
    k_pack_M<<<NKV * 6 * 12, 256, 0, stream>>>(Mp, Mm, Mpk);
    k_build_T<<<NKV * 16, 256, 0, stream>>>(phi, Tpk);
    hipMemsetAsync(outz, 0, (size_t)NZC * SEQ * DDIM * 4, stream);

    for (int kvLo = 0; kvLo < NKV; kvLo += C) {
        k_gemm_A<<<C * 96, 256, 0, stream>>>(Mpk, xpk, Apk, kvLo);
        k_gemm_Bv4<<<432, 256, 0, stream>>>(Tpk, Apk, outz, kvLo, C);
    }
    int n4 = SEQ * DDIM / 4;
    k_reduce<<<(n4 + 255) / 256, 256, 0, stream>>>(outz, out, n4);
}

// Round 5
// 360.806 us; speedup vs baseline: 2.1615x; 1.0065x over previous
//
#include <hip/hip_runtime.h>
#include <hip/hip_bf16.h>
#include <stdint.h>

#define SEQ 2048
#define DDIM 768
#define KF 24
#define NKV 48
#define NZC 8   // outz split-K slices (jj-chunk of 2)

typedef unsigned short ushort_t;
typedef __attribute__((ext_vector_type(8))) short short8;
typedef __attribute__((ext_vector_type(4))) float f32x4;

typedef __attribute__((address_space(3))) uint32_t lds_u32;
typedef __attribute__((address_space(1))) uint32_t glb_u32;

__device__ __forceinline__ unsigned short f2bf(float f) {
    union { float f; uint32_t u; } v; v.f = f;
    uint32_t u = v.u;
    return (unsigned short)((u + 0x7fff + ((u >> 16) & 1)) >> 16);
}

// Image layout for a [128 rows][64 k] bf16 slab (16 KB), XOR-swizzled:
//   idx(row,k) = row*64 + (((k>>3) ^ (row&7))<<3) + (k&7)

// ---------------- prep: pack x ----------------
__global__ void k_pack_x(const float* __restrict__ x, ushort_t* __restrict__ xpk) {
    int b = blockIdx.x;            // tt*12 + ks
    int tt = b / 12, ks = b % 12;
    int tid = threadIdx.x;
    ushort_t* dst = xpk + (size_t)b * 8192;
    const float* src = x + (size_t)tt * 128 * DDIM + ks * 64;
#pragma unroll
    for (int p = 0; p < 4; ++p) {
        int s = p * 256 + tid;
        int row = s >> 3, sl = s & 7;
        const float* rp = src + (size_t)row * DDIM + sl * 8;
        float4 a = *(const float4*)rp;
        float4 c = *(const float4*)(rp + 4);
        ushort_t v[8] = {f2bf(a.x), f2bf(a.y), f2bf(a.z), f2bf(a.w),
                         f2bf(c.x), f2bf(c.y), f2bf(c.z), f2bf(c.w)};
        *(uint4*)(dst + row * 64 + ((sl ^ (row & 7)) << 3)) = *(uint4*)v;
    }
}

// ---------------- prep: pack M transposed ----------------
__global__ void k_pack_M(const float* __restrict__ Mp, const float* __restrict__ Mm,
                         ushort_t* __restrict__ Mpk) {
    __shared__ ushort_t lt[128 * 66];
    int b = blockIdx.x;            // (kv*6 + et)*12 + ks
    int kv = b / 72; int rem = b % 72; int et = rem / 12, ks = rem % 12;
    const float* src = ((kv < KF) ? Mp + (size_t)kv * DDIM * DDIM
                                  : Mm + (size_t)(kv - KF) * DDIM * DDIM)
                       + (size_t)(ks * 64) * DDIM + et * 128;
    int tid = threadIdx.x;
#pragma unroll
    for (int p = 0; p < 32; ++p) {
        int lin = p * 256 + tid;
        int d = lin >> 7, e = lin & 127;
        lt[e * 66 + d] = f2bf(src[(size_t)d * DDIM + e]);
    }
    __syncthreads();
    ushort_t* dst = Mpk + (size_t)b * 8192;
#pragma unroll
    for (int p = 0; p < 4; ++p) {
        int s = p * 256 + tid; int row = s >> 3, sl = s & 7;
        ushort_t v[8];
#pragma unroll
        for (int j = 0; j < 8; ++j) v[j] = lt[row * 66 + sl * 8 + j];
        *(uint4*)(dst + row * 64 + ((sl ^ (row & 7)) << 3)) = *(uint4*)v;
    }
}

// ---------------- prep: build Toeplitz blocks ----------------
__global__ void k_build_T(const float* __restrict__ phi, ushort_t* __restrict__ Tpk) {
    __shared__ float phiL[256];
    int b = blockIdx.x;            // kv*16 + lag
    int kv = b >> 4, dm = b & 15;
    int k = kv % KF; bool neg = kv >= KF;
    int tid = threadIdx.x;
    int tau = 128 * dm - 127 + tid;
    float v = 0.f;
    if (tid < 255 && tau >= 0 && tau < SEQ) {
        v = phi[(size_t)tau * KF + k];
        if (neg && (tau & 1)) v = -v;
    }
    phiL[tid] = v;
    __syncthreads();
    ushort_t* dst = Tpk + (size_t)b * 2 * 8192;
#pragma unroll
    for (int h = 0; h < 2; ++h) {
#pragma unroll
        for (int p = 0; p < 4; ++p) {
            int s = p * 256 + tid; int row = s >> 3, sl = s & 7;
            ushort_t v8[8];
#pragma unroll
            for (int j = 0; j < 8; ++j) {
                int col = h * 64 + sl * 8 + j;
                v8[j] = f2bf(phiL[row - col + 127]);
            }
            *(uint4*)(dst + h * 8192 + row * 64 + ((sl ^ (row & 7)) << 3)) = *(uint4*)v8;
        }
    }
}

// ---------------- shared fragment-read helpers ----------------

__device__ __forceinline__ void read_frags(const ushort_t* As, const ushort_t* Bs,
                                           int lane, int wm, int wn, int kk,
                                           short8 av[4], short8 bv[4]) {
    int slot = kk * 4 + (lane >> 4);
#pragma unroll
    for (int m = 0; m < 4; ++m) {
        int row = wm * 64 + m * 16 + (lane & 15);
        av[m] = *(const short8*)(As + row * 64 + ((slot ^ (row & 7)) << 3));
    }
#pragma unroll
    for (int n = 0; n < 4; ++n) {
        int row = wn * 64 + n * 16 + (lane & 15);
        bv[n] = *(const short8*)(Bs + row * 64 + ((slot ^ (row & 7)) << 3));
    }
}

__device__ __forceinline__ void mfma16(const short8 av[4], const short8 bv[4], f32x4 acc[4][4]) {
    __builtin_amdgcn_s_setprio(1);
#pragma unroll
    for (int m = 0; m < 4; ++m)
#pragma unroll
        for (int n = 0; n < 4; ++n)
            acc[m][n] = __builtin_amdgcn_mfma_f32_16x16x32_bf16(av[m], bv[n], acc[m][n], 0, 0, 0);
    __builtin_amdgcn_s_setprio(0);
}

// ---------------- stage A v5: pipelined, sub-phased ----------------
// Apk[kvi][et][tt][h][img] = (M_kv^T x^T) tile
__global__ __launch_bounds__(256, 2)
void k_gemm_A(const ushort_t* __restrict__ Mpk, const ushort_t* __restrict__ xpk,
              ushort_t* __restrict__ Apk, int kvLo) {
    __shared__ ushort_t smem[2][2][8192];
    int bid = blockIdx.x;
    int kvi = bid / 96; int rem = bid % 96; int et = rem / 16, tt = rem % 16;
    int kv = kvLo + kvi;
    const ushort_t* Abase = Mpk + ((size_t)(kv * 6 + et) * 12) * 8192;
    const ushort_t* Bbase = xpk + (size_t)(tt * 12) * 8192;
    int tid = threadIdx.x, lane = tid & 63, wave = tid >> 6;
    int wm = wave >> 1, wn = wave & 1;

    auto stage4 = [&](const ushort_t* src, ushort_t* dst) {
        const char* s = (const char*)src + wave * 4096 + lane * 16;
        char* l = (char*)dst + wave * 4096;
#pragma unroll
        for (int p = 0; p < 4; ++p)
            __builtin_amdgcn_global_load_lds((const glb_u32*)(s + p * 1024),
                                             (lds_u32*)(l + p * 1024), 16, 0, 0);
    };

    f32x4 acc[4][4];
#pragma unroll
    for (int m = 0; m < 4; ++m)
#pragma unroll
        for (int n = 0; n < 4; ++n) acc[m][n] = (f32x4){0.f, 0.f, 0.f, 0.f};

    stage4(Abase, smem[0][0]);
    stage4(Bbase, smem[0][1]);

    for (int s = 0; s < 12; ++s) {
        int c = s & 1;
        bool more = (s + 1 < 12);
        if (more) {
            stage4(Abase + (s + 1) * 8192, smem[c ^ 1][0]);
            asm volatile("s_waitcnt vmcnt(4)" ::: "memory");
        } else {
            asm volatile("s_waitcnt vmcnt(0)" ::: "memory");
        }
        __builtin_amdgcn_s_barrier();
        __builtin_amdgcn_sched_barrier(0);

        const ushort_t* As = smem[c][0];
        const ushort_t* Bs = smem[c][1];
        short8 av0[4], bv0[4], av1[4], bv1[4];
        read_frags(As, Bs, lane, wm, wn, 0, av0, bv0);
        asm volatile("s_waitcnt lgkmcnt(0)" ::: "memory");
        __builtin_amdgcn_sched_barrier(0);
        read_frags(As, Bs, lane, wm, wn, 1, av1, bv1);
        if (more) stage4(Bbase + (s + 1) * 8192, smem[c ^ 1][1]);
        mfma16(av0, bv0, acc);                      // overlaps av1/bv1 reads
        asm volatile("s_waitcnt lgkmcnt(0)" ::: "memory");
        __builtin_amdgcn_sched_barrier(0);
        mfma16(av1, bv1, acc);
        __builtin_amdgcn_s_barrier();
    }

    // repack C tile (rows=e, cols=t) into packed image pair in LDS, stream out
    ushort_t* sm = &smem[0][0][0];
#pragma unroll
    for (int m = 0; m < 4; ++m) {
        int rb = wm * 64 + m * 16 + ((lane >> 4) << 2);
#pragma unroll
        for (int n = 0; n < 4; ++n) {
            int cb = wn * 64 + n * 16 + (lane & 15);
            int h = cb >> 6, c6 = cb & 63, sl = c6 >> 3, j = c6 & 7;
#pragma unroll
            for (int r = 0; r < 4; ++r) {
                int row = rb + r;
                sm[h * 8192 + row * 64 + ((sl ^ (row & 7)) << 3) + j] = f2bf(acc[m][n][r]);
            }
        }
    }
    __syncthreads();
    uint4* d4 = (uint4*)(Apk + ((size_t)((kvi * 6 + et) * 16 + tt) * 2) * 8192);
    const uint4* s4 = (const uint4*)sm;
#pragma unroll
    for (int p = 0; p < 8; ++p) d4[p * 256 + tid] = s4[p * 256 + tid];
}

// ---------------- stage B v5: pipelined, sub-phased, store/accum ----------------
__global__ __launch_bounds__(256, 2)
void k_gemm_Bv5(const ushort_t* __restrict__ Tpk, const ushort_t* __restrict__ Apk,
                float* __restrict__ outz, int kvLo, int nkv, int accum) {
    __shared__ ushort_t smem[2][2][8192];   // [buf][0=T, 1=A]

    int bid = blockIdx.x;                    // bijective XCD swizzle: 432 = 8*54
    int lid = (bid & 7) * 54 + (bid >> 3);
    int et = lid / 72;
    int cidx = lid % 72;
    int i1 = 0, zc = 0, base = 0;
#pragma unroll
    for (int t = 0; t < 16; ++t) {           // heaviest i1 first
        int cand = 15 - t;
        int nc = (cand >> 1) + 1;
        if (cidx < base + nc) { i1 = cand; zc = cidx - base; break; }
        base += nc;
    }
    int jlo = zc * 2;
    int jhi = (jlo + 1 < i1) ? (jlo + 1) : i1;
    int NS = nkv * (jhi - jlo + 1) * 2;

    int tid = threadIdx.x, lane = tid & 63, wave = tid >> 6;
    int wm = wave >> 1, wn = wave & 1;

    f32x4 acc[4][4];
#pragma unroll
    for (int m = 0; m < 4; ++m)
#pragma unroll
        for (int n = 0; n < 4; ++n) acc[m][n] = (f32x4){0.f, 0.f, 0.f, 0.f};

    auto timg = [&](int kv, int jj, int h) -> const ushort_t* {
        return Tpk + ((size_t)(((kvLo + kv) * 16 + (i1 - jj)) * 2 + h)) * 8192;
    };
    auto aimg = [&](int kv, int jj, int h) -> const ushort_t* {
        return Apk + ((size_t)(((kv * 6 + et) * 16 + jj) * 2 + h)) * 8192;
    };
    auto stage4 = [&](const ushort_t* src, ushort_t* dst) {
        const char* s = (const char*)src + wave * 4096 + lane * 16;
        char* l = (char*)dst + wave * 4096;
#pragma unroll
        for (int p = 0; p < 4; ++p)
            __builtin_amdgcn_global_load_lds((const glb_u32*)(s + p * 1024),
                                             (lds_u32*)(l + p * 1024), 16, 0, 0);
    };

    int kv = 0, jj = jlo, h = 0;
    stage4(timg(kv, jj, h), smem[0][0]);
    stage4(aimg(kv, jj, h), smem[0][1]);

    for (int s = 0; s < NS; ++s) {
        int c = s & 1;
        int nh = h ^ 1, njj = jj, nkvv = kv;
        if (!nh) { njj = jj + 1; if (njj > jhi) { njj = jlo; nkvv = kv + 1; } }
        bool more = (s + 1 < NS);

        if (more) {
            stage4(timg(nkvv, njj, nh), smem[c ^ 1][0]);
            asm volatile("s_waitcnt vmcnt(4)" ::: "memory");
        } else {
            asm volatile("s_waitcnt vmcnt(0)" ::: "memory");
        }
        __builtin_amdgcn_s_barrier();
        __builtin_amdgcn_sched_barrier(0);

        const ushort_t* As = smem[c][0];
        const ushort_t* Bs = smem[c][1];
        short8 av0[4], bv0[4], av1[4], bv1[4];
        read_frags(As, Bs, lane, wm, wn, 0, av0, bv0);
        asm volatile("s_waitcnt lgkmcnt(0)" ::: "memory");
        __builtin_amdgcn_sched_barrier(0);
        read_frags(As, Bs, lane, wm, wn, 1, av1, bv1);
        if (more) stage4(aimg(nkvv, njj, nh), smem[c ^ 1][1]);
        mfma16(av0, bv0, acc);                      // overlaps av1/bv1 reads
        asm volatile("s_waitcnt lgkmcnt(0)" ::: "memory");
        __builtin_amdgcn_sched_barrier(0);
        mfma16(av1, bv1, acc);
        __builtin_amdgcn_s_barrier();
        kv = nkvv; jj = njj; h = nh;
    }

    float* dst = outz + ((size_t)zc * SEQ + (size_t)i1 * 128) * DDIM + et * 128;
#pragma unroll
    for (int m = 0; m < 4; ++m) {
        int rb = wm * 64 + m * 16 + ((lane >> 4) << 2);
#pragma unroll
        for (int n = 0; n < 4; ++n) {
            int cb = wn * 64 + n * 16 + (lane & 15);
#pragma unroll
            for (int r = 0; r < 4; ++r) {
                float* p = dst + (size_t)(rb + r) * DDIM + cb;
                float v = acc[m][n][r];
                if (accum) v += *p;
                *p = v;
            }
        }
    }
}

// sum only z-slices that were written for this row: zc <= (s>>7)/2
__global__ void k_reduce(const float* __restrict__ outz, float* __restrict__ out, int n4) {
    int idx = blockIdx.x * blockDim.x + threadIdx.x;
    if (idx < n4) {
        int srow = idx / (DDIM / 4);
        int zmax = (srow >> 8);            // (s>>7)>>1
        if (zmax > NZC - 1) zmax = NZC - 1;
        float4 s = ((const float4*)outz)[idx];
        for (int z = 1; z <= zmax; ++z) {
            float4 t = ((const float4*)(outz + (size_t)z * SEQ * DDIM))[idx];
            s.x += t.x; s.y += t.y; s.z += t.z; s.w += t.w;
        }
        ((float4*)out)[idx] = s;
    }
}

extern "C" void kernel_launch(void* const* d_in, const int* in_sizes, int n_in,
                              void* d_out, int out_size, void* d_ws, size_t ws_size,
                              hipStream_t stream) {
    (void)in_sizes; (void)n_in;
    const float* x   = (const float*)d_in[0];
    const float* phi = (const float*)d_in[1];
    const float* Mp  = (const float*)d_in[2];
    const float* Mm  = (const float*)d_in[3];
    float* out = (float*)d_out;

    char* ws = (char*)d_ws;
    size_t off = 0;
    auto alloc = [&](size_t bytes) { size_t o = off; off += (bytes + 255) & ~(size_t)255; return o; };
    size_t o_xpk  = alloc((size_t)16 * 12 * 8192 * 2);
    size_t o_Mpk  = alloc((size_t)NKV * 6 * 12 * 8192 * 2);
    size_t o_Tpk  = alloc((size_t)NKV * 16 * 2 * 8192 * 2);
    size_t o_outz = alloc((size_t)NZC * SEQ * DDIM * 4);
    size_t fixed = off;

    int C = 0;
    const int cand[4] = {48, 24, 16, 8};
    for (int ci = 0; ci < 4; ++ci) {
        if (fixed + (size_t)cand[ci] * 6 * 16 * 2 * 8192 * 2 <= ws_size) { C = cand[ci]; break; }
    }
    if (C == 0) {
        hipMemsetAsync(d_out, 0, (size_t)out_size * 4, stream);
        return;
    }
    size_t o_Apk = alloc((size_t)C * 6 * 16 * 2 * 8192 * 2);

    ushort_t* xpk = (ushort_t*)(ws + o_xpk);
    ushort_t* Mpk = (ushort_t*)(ws + o_Mpk);
    ushort_t* Tpk = (ushort_t*)(ws + o_Tpk);
    float*    outz = (float*)(ws + o_outz);
    ushort_t* Apk = (ushort_t*)(ws + o_Apk);

    k_pack_x<<<16 * 12, 256, 0, stream>>>(x, xpk);
    k_pack_M<<<NKV * 6 * 12, 256, 0, stream>>>(Mp, Mm, Mpk);
    k_build_T<<<NKV * 16, 256, 0, stream>>>(phi, Tpk);

    for (int kvLo = 0; kvLo < NKV; kvLo += C) {
        k_gemm_A<<<C * 96, 256, 0, stream>>>(Mpk, xpk, Apk, kvLo);
        k_gemm_Bv5<<<432, 256, 0, stream>>>(Tpk, Apk, outz, kvLo, C, kvLo > 0);
    }
    int n4 = SEQ * DDIM / 4;
    k_reduce<<<(n4 + 255) / 256, 256, 0, stream>>>(outz, out, n4);
}